// Round 8
// baseline (478.642 us; speedup 1.0000x reference)
//
#include <hip/hip_runtime.h>

typedef unsigned short u16;
typedef u16 u16x4 __attribute__((ext_vector_type(4)));
typedef __bf16 bf16x8 __attribute__((ext_vector_type(8)));
typedef float f32x4 __attribute__((ext_vector_type(4)));

#define NROW 8192
#define CAP 128
#define D_IN 512
#define D_HID 256
#define D_OUT 128

__device__ __forceinline__ float leaky_f(float x) { return x > 0.f ? x : 0.25f * x; }

__device__ __forceinline__ u16 f2bf_rne(float f) {
  unsigned u = __float_as_uint(f);
  u += 0x7fffu + ((u >> 16) & 1u);
  return (u16)(u >> 16);
}
__device__ __forceinline__ float bf2f(u16 v) { return __uint_as_float(((unsigned)v) << 16); }
__device__ __forceinline__ void split_bf16(float f, u16& hi, u16& lo) {
  hi = f2bf_rne(f);
  float fh = __uint_as_float(((unsigned)hi) << 16);
  lo = f2bf_rne(f - fh);
}

// ---------------- weight pack: W1/W2/Wg -> [hi(K)|lo(K)] transposed rows ----------------
__global__ __launch_bounds__(256) void k_packw(
    const float* __restrict__ W1, u16* __restrict__ B1,
    const float* __restrict__ W2, u16* __restrict__ B2,
    const float* __restrict__ Wg, u16* __restrict__ B3) {
  const float* W; u16* Bt; int K, Nc, id;
  int pb = blockIdx.x;                     // 896 blocks: 512 | 256 | 128
  if (pb < 512)      { W = W1; Bt = B1; K = D_IN;  Nc = D_HID; id = pb * 256 + threadIdx.x; }
  else if (pb < 768) { W = W2; Bt = B2; K = D_HID; Nc = D_HID; id = (pb - 512) * 256 + threadIdx.x; }
  else               { W = Wg; Bt = B3; K = D_HID; Nc = D_OUT; id = (pb - 768) * 256 + threadIdx.x; }
  int n = id % Nc, k = id / Nc;
  float f = W[id];
  u16 hi, lo; split_bf16(f, hi, lo);
  size_t ro = (size_t)n * 2 * K;
  Bt[ro + k] = hi; Bt[ro + K + k] = lo;
}

// ---------------- merged: blocks [0,512) = GEMM1 (x @ W1), blocks [512,8704) = CSR build ----------------
__global__ __launch_bounds__(256) void k_csr_gemm1(const float* __restrict__ adj,
    int* __restrict__ cnt, int* __restrict__ cols, float* __restrict__ vals,
    const float* __restrict__ X, const u16* __restrict__ Bt, float* __restrict__ C) {
  __shared__ u16 Ah[64 * 40], Al[64 * 40];
  __shared__ u16 Bh[64 * 40], Bl[64 * 40];
  __shared__ int csrc;
  int b = blockIdx.x;
  int tid = threadIdx.x;
  if (b < 512) {  // GEMM1: 64x64 tile, in-register fp32->split-bf16 of x; K=512, N=256
    const int N = D_HID, K = D_IN;
    int bm = (b >> 2) * 64, bn = (b & 3) * 64;
    int wave = tid >> 6, lane = tid & 63, l15 = lane & 15, quad = lane >> 4;
    f32x4 acc[4] = {};
    int ar = tid >> 2, aj = (tid & 3) << 3;
    const float* Xrow = X + (size_t)(bm + ar) * K + aj;
    const u16* Brow = Bt + (size_t)(bn + ar) * (2 * K) + aj;
    for (int k0 = 0; k0 < K; k0 += 32) {
      alignas(16) u16 hh[8], ll[8];
      float xv[8];
      *(float4*)(xv)     = *(const float4*)(Xrow + k0);
      *(float4*)(xv + 4) = *(const float4*)(Xrow + k0 + 4);
#pragma unroll
      for (int e = 0; e < 8; ++e) split_bf16(xv[e], hh[e], ll[e]);
      *(uint4*)(&Ah[ar * 40 + aj]) = *(const uint4*)hh;
      *(uint4*)(&Al[ar * 40 + aj]) = *(const uint4*)ll;
      *(uint4*)(&Bh[ar * 40 + aj]) = *(const uint4*)(Brow + k0);
      *(uint4*)(&Bl[ar * 40 + aj]) = *(const uint4*)(Brow + K + k0);
      __syncthreads();
      bf16x8 afh = *(const bf16x8*)(&Ah[(wave * 16 + l15) * 40 + quad * 8]);
      bf16x8 afl = *(const bf16x8*)(&Al[(wave * 16 + l15) * 40 + quad * 8]);
#pragma unroll
      for (int c = 0; c < 4; ++c) {
        bf16x8 bfh = *(const bf16x8*)(&Bh[(c * 16 + l15) * 40 + quad * 8]);
        bf16x8 bfl = *(const bf16x8*)(&Bl[(c * 16 + l15) * 40 + quad * 8]);
        acc[c] = __builtin_amdgcn_mfma_f32_16x16x32_bf16(afh, bfh, acc[c], 0, 0, 0);
        acc[c] = __builtin_amdgcn_mfma_f32_16x16x32_bf16(afh, bfl, acc[c], 0, 0, 0);
        acc[c] = __builtin_amdgcn_mfma_f32_16x16x32_bf16(afl, bfh, acc[c], 0, 0, 0);
      }
      __syncthreads();
    }
#pragma unroll
    for (int c = 0; c < 4; ++c)
#pragma unroll
      for (int rg = 0; rg < 4; ++rg) {
        int rowi = bm + wave * 16 + quad * 4 + rg;   // C/D: col=lane&15, row=quad*4+reg
        int coli = bn + c * 16 + l15;
        C[(size_t)rowi * N + coli] = acc[c][rg];
      }
    return;
  }
  // CSR row build
  int i = b - 512;
  if (tid == 0) csrc = 0;
  __syncthreads();
  const float4* row = (const float4*)(adj + (size_t)i * NROW);
  for (int j4 = tid; j4 < NROW / 4; j4 += 256) {
    float4 v = row[j4];
    int base = j4 * 4;
    if (v.x > 0.f) { int s = atomicAdd(&csrc, 1); if (s < CAP) { cols[i*CAP+s] = base;   vals[i*CAP+s] = v.x; } }
    if (v.y > 0.f) { int s = atomicAdd(&csrc, 1); if (s < CAP) { cols[i*CAP+s] = base+1; vals[i*CAP+s] = v.y; } }
    if (v.z > 0.f) { int s = atomicAdd(&csrc, 1); if (s < CAP) { cols[i*CAP+s] = base+2; vals[i*CAP+s] = v.z; } }
    if (v.w > 0.f) { int s = atomicAdd(&csrc, 1); if (s < CAP) { cols[i*CAP+s] = base+3; vals[i*CAP+s] = v.w; } }
  }
  __syncthreads();
  if (tid == 0) cnt[i] = (csrc < CAP) ? csrc : CAP;
}

// ---------------- fused SpMM+GEMM2: T2[16 rows] = leaky(adj@H0 + b1) @ W2 ----------------
// 512 blocks x 16 rows. Phase 1: per-wave 4-row gather -> split-bf16 LDS A-tile (stride 264,
// 2-way bank max). Phase 2: K=256 MFMA vs L2-hot B2t, 16x256 out.
__global__ __launch_bounds__(256) void k_spmm_gemm2(const float* __restrict__ Hin,
    const float* __restrict__ bias, const int* __restrict__ cnt,
    const int* __restrict__ cols, const float* __restrict__ vals,
    const u16* __restrict__ Bt, float* __restrict__ T2) {
  __shared__ u16 Ahh[16 * 264], All[16 * 264];   // 16.9 KB
  __shared__ u16 Bh[256 * 40], Bl[256 * 40];     // 40 KB
  __shared__ int scw[4][CAP];
  __shared__ float svw[4][CAP];
  int tid = threadIdx.x, wave = tid >> 6, lane = tid & 63;
  int base = blockIdx.x * 16;
  const float4* H4 = (const float4*)Hin;
  float4 bv = ((const float4*)bias)[lane];
  // phase 1: wave w -> rows base + w*4 .. +4
  for (int rr = 0; rr < 4; ++rr) {
    int row = base + wave * 4 + rr;
    int n = cnt[row];
    if (lane < n)      { scw[wave][lane]      = cols[row*CAP+lane];      svw[wave][lane]      = vals[row*CAP+lane]; }
    if (lane + 64 < n) { scw[wave][lane+64]   = cols[row*CAP+lane+64];   svw[wave][lane+64]   = vals[row*CAP+lane+64]; }
    __syncthreads();
    float4 acc = {0.f, 0.f, 0.f, 0.f};
    for (int k = 0; k < n; ++k) {
      float w = svw[wave][k];
      float4 v = H4[(size_t)scw[wave][k] * 64 + lane];
      acc.x = fmaf(w, v.x, acc.x); acc.y = fmaf(w, v.y, acc.y);
      acc.z = fmaf(w, v.z, acc.z); acc.w = fmaf(w, v.w, acc.w);
    }
    float r[4] = { leaky_f(acc.x + bv.x), leaky_f(acc.y + bv.y),
                   leaky_f(acc.z + bv.z), leaky_f(acc.w + bv.w) };
    u16x4 hi4, lo4;
#pragma unroll
    for (int e = 0; e < 4; ++e) { u16 hh, ll; split_bf16(r[e], hh, ll); hi4[e] = hh; lo4[e] = ll; }
    int ra = wave * 4 + rr;
    *(u16x4*)(&Ahh[ra * 264 + lane * 4]) = hi4;
    *(u16x4*)(&All[ra * 264 + lane * 4]) = lo4;
    __syncthreads();
  }
  // phase 2: mini-GEMM 16 x 256, K=256
  int l15 = lane & 15, quad = lane >> 4;
  f32x4 acc2[4] = {};
  for (int k0 = 0; k0 < 256; k0 += 32) {
    const u16* Brow = Bt + (size_t)tid * 512 + k0;
#pragma unroll
    for (int j = 0; j < 4; ++j) {
      *(uint4*)(&Bh[tid * 40 + j * 8]) = *(const uint4*)(Brow + j * 8);
      *(uint4*)(&Bl[tid * 40 + j * 8]) = *(const uint4*)(Brow + 256 + j * 8);
    }
    __syncthreads();
    bf16x8 afh = *(const bf16x8*)(&Ahh[l15 * 264 + k0 + quad * 8]);
    bf16x8 afl = *(const bf16x8*)(&All[l15 * 264 + k0 + quad * 8]);
#pragma unroll
    for (int c = 0; c < 4; ++c) {
      bf16x8 bfh = *(const bf16x8*)(&Bh[(wave * 64 + c * 16 + l15) * 40 + quad * 8]);
      bf16x8 bfl = *(const bf16x8*)(&Bl[(wave * 64 + c * 16 + l15) * 40 + quad * 8]);
      acc2[c] = __builtin_amdgcn_mfma_f32_16x16x32_bf16(afh, bfh, acc2[c], 0, 0, 0);
      acc2[c] = __builtin_amdgcn_mfma_f32_16x16x32_bf16(afh, bfl, acc2[c], 0, 0, 0);
      acc2[c] = __builtin_amdgcn_mfma_f32_16x16x32_bf16(afl, bfh, acc2[c], 0, 0, 0);
    }
    __syncthreads();
  }
#pragma unroll
  for (int c = 0; c < 4; ++c)
#pragma unroll
    for (int rg = 0; rg < 4; ++rg) {
      int rowi = base + quad * 4 + rg;           // C/D: col=lane&15, row=quad*4+reg (M=16)
      int coli = wave * 64 + c * 16 + l15;
      T2[(size_t)rowi * 256 + coli] = acc2[c][rg];
    }
}

// ---------------- fused SpMM+GEMM3: h(bf16)[16 rows] = leaky(adj@T2 + b2) @ Wg, + fp32 s1/s2 ----------------
__global__ __launch_bounds__(256) void k_spmm_gemm3(const float* __restrict__ Hin,
    const float* __restrict__ bias, const int* __restrict__ cnt,
    const int* __restrict__ cols, const float* __restrict__ vals,
    const u16* __restrict__ Bt, u16* __restrict__ Hb,
    const float* __restrict__ aptr, float* __restrict__ s1, float* __restrict__ s2) {
  __shared__ u16 Ahh[16 * 264], All[16 * 264];   // 16.9 KB
  __shared__ u16 Bh[128 * 40], Bl[128 * 40];     // 20 KB
  __shared__ int scw[4][CAP];
  __shared__ float svw[4][CAP];
  __shared__ float sp1[4][16], sp2[4][16];
  int tid = threadIdx.x, wave = tid >> 6, lane = tid & 63;
  int base = blockIdx.x * 16;
  const float4* H4 = (const float4*)Hin;
  float4 bv = ((const float4*)bias)[lane];
  for (int rr = 0; rr < 4; ++rr) {
    int row = base + wave * 4 + rr;
    int n = cnt[row];
    if (lane < n)      { scw[wave][lane]      = cols[row*CAP+lane];      svw[wave][lane]      = vals[row*CAP+lane]; }
    if (lane + 64 < n) { scw[wave][lane+64]   = cols[row*CAP+lane+64];   svw[wave][lane+64]   = vals[row*CAP+lane+64]; }
    __syncthreads();
    float4 acc = {0.f, 0.f, 0.f, 0.f};
    for (int k = 0; k < n; ++k) {
      float w = svw[wave][k];
      float4 v = H4[(size_t)scw[wave][k] * 64 + lane];
      acc.x = fmaf(w, v.x, acc.x); acc.y = fmaf(w, v.y, acc.y);
      acc.z = fmaf(w, v.z, acc.z); acc.w = fmaf(w, v.w, acc.w);
    }
    float r[4] = { leaky_f(acc.x + bv.x), leaky_f(acc.y + bv.y),
                   leaky_f(acc.z + bv.z), leaky_f(acc.w + bv.w) };
    u16x4 hi4, lo4;
#pragma unroll
    for (int e = 0; e < 4; ++e) { u16 hh, ll; split_bf16(r[e], hh, ll); hi4[e] = hh; lo4[e] = ll; }
    int ra = wave * 4 + rr;
    *(u16x4*)(&Ahh[ra * 264 + lane * 4]) = hi4;
    *(u16x4*)(&All[ra * 264 + lane * 4]) = lo4;
    __syncthreads();
  }
  // phase 2: mini-GEMM 16 x 128, K=256
  int l15 = lane & 15, quad = lane >> 4;
  f32x4 acc2[2] = {};
  for (int k0 = 0; k0 < 256; k0 += 32) {
    int n = tid & 127, half = tid >> 7;            // 128 rows x 2 bufs
    const u16* Brow = Bt + (size_t)n * 512 + half * 256 + k0;
    u16* dst = (half ? Bl : Bh) + n * 40;
#pragma unroll
    for (int j = 0; j < 4; ++j)
      *(uint4*)(dst + j * 8) = *(const uint4*)(Brow + j * 8);
    __syncthreads();
    bf16x8 afh = *(const bf16x8*)(&Ahh[l15 * 264 + k0 + quad * 8]);
    bf16x8 afl = *(const bf16x8*)(&All[l15 * 264 + k0 + quad * 8]);
#pragma unroll
    for (int c = 0; c < 2; ++c) {
      bf16x8 bfh = *(const bf16x8*)(&Bh[((wave * 2 + c) * 16 + l15) * 40 + quad * 8]);
      bf16x8 bfl = *(const bf16x8*)(&Bl[((wave * 2 + c) * 16 + l15) * 40 + quad * 8]);
      acc2[c] = __builtin_amdgcn_mfma_f32_16x16x32_bf16(afh, bfh, acc2[c], 0, 0, 0);
      acc2[c] = __builtin_amdgcn_mfma_f32_16x16x32_bf16(afh, bfl, acc2[c], 0, 0, 0);
      acc2[c] = __builtin_amdgcn_mfma_f32_16x16x32_bf16(afl, bfh, acc2[c], 0, 0, 0);
    }
    __syncthreads();
  }
  // h write (bf16; logits below from fp32 accs)
#pragma unroll
  for (int c = 0; c < 2; ++c)
#pragma unroll
    for (int rg = 0; rg < 4; ++rg) {
      int rowi = base + quad * 4 + rg;
      int coli = wave * 32 + c * 16 + l15;
      Hb[(size_t)rowi * 128 + coli] = f2bf_rne(acc2[c][rg]);
    }
  // fused s1/s2 (fp32 logit path)
  float a1v[2], a2v[2];
#pragma unroll
  for (int c = 0; c < 2; ++c) {
    a1v[c] = aptr[wave * 32 + c * 16 + l15];
    a2v[c] = aptr[128 + wave * 32 + c * 16 + l15];
  }
#pragma unroll
  for (int rg = 0; rg < 4; ++rg) {
    float p1 = fmaf(acc2[0][rg], a1v[0], acc2[1][rg] * a1v[1]);
    float p2 = fmaf(acc2[0][rg], a2v[0], acc2[1][rg] * a2v[1]);
#pragma unroll
    for (int m = 1; m < 16; m <<= 1) { p1 += __shfl_xor(p1, m); p2 += __shfl_xor(p2, m); }
    if (l15 == 0) { sp1[wave][quad * 4 + rg] = p1; sp2[wave][quad * 4 + rg] = p2; }
  }
  __syncthreads();
  if (tid < 16) {
    s1[base + tid] = sp1[0][tid] + sp1[1][tid] + sp1[2][tid] + sp1[3][tid];
    s2[base + tid] = sp2[0][tid] + sp2[1][tid] + sp2[2][tid] + sp2[3][tid];
  }
}

// ---------------- attention: fp32 logits, bf16 h gather, mu/logvar split ----------------
__global__ __launch_bounds__(128) void k_attn(const u16* __restrict__ Hb,
    const float* __restrict__ s1, const float* __restrict__ s2,
    const int* __restrict__ cnt, const int* __restrict__ cols, float* __restrict__ out) {
  int i = blockIdx.x, t = threadIdx.x;
  int t32 = t & 31, g = t >> 5;
  __shared__ int sc[CAP];
  __shared__ float sw[CAP];
  __shared__ float sred[2];
  __shared__ float4 sacc[4][32];
  int n = cnt[i];
  float s1i = s1[i];
  if (t < n) { int c = cols[i * CAP + t]; sc[t] = c; sw[t] = leaky_f(s1i + s2[c]); }
  __syncthreads();
  if (t < 64) {
    float m = -1e30f;
    if (t < n) m = sw[t];
    if (t + 64 < n) m = fmaxf(m, sw[t + 64]);
    for (int o = 32; o > 0; o >>= 1) m = fmaxf(m, __shfl_down(m, o));
    if (t == 0) sred[0] = m;
  }
  __syncthreads();
  float mx = sred[0];
  if (t < n) sw[t] = expf(sw[t] - mx);
  __syncthreads();
  if (t < 64) {
    float s = 0.f;
    if (t < n) s = sw[t];
    if (t + 64 < n) s += sw[t + 64];
    for (int o = 32; o > 0; o >>= 1) s += __shfl_down(s, o);
    if (t == 0) sred[1] = s;
  }
  __syncthreads();
  float inv = (n > 0) ? 1.0f / sred[1] : 0.f;
  float4 acc = {0.f, 0.f, 0.f, 0.f};
  for (int k = g; k < n; k += 4) {
    float w = sw[k];
    u16x4 v = *(const u16x4*)(Hb + (size_t)sc[k] * 128 + 4 * t32);
    acc.x = fmaf(w, bf2f(v[0]), acc.x); acc.y = fmaf(w, bf2f(v[1]), acc.y);
    acc.z = fmaf(w, bf2f(v[2]), acc.z); acc.w = fmaf(w, bf2f(v[3]), acc.w);
  }
  sacc[g][t32] = acc;
  __syncthreads();
  if (t < 32) {
    float4 a0 = sacc[0][t], a1 = sacc[1][t], a2 = sacc[2][t], a3 = sacc[3][t];
    float4 r;
    r.x = leaky_f((a0.x + a1.x + a2.x + a3.x) * inv);
    r.y = leaky_f((a0.y + a1.y + a2.y + a3.y) * inv);
    r.z = leaky_f((a0.z + a1.z + a2.z + a3.z) * inv);
    r.w = leaky_f((a0.w + a1.w + a2.w + a3.w) * inv);
    float4* o4 = (float4*)out;
    if (t < 16) o4[(size_t)i * 16 + t] = r;                               // mu
    else        o4[(size_t)NROW * 16 + (size_t)i * 16 + (t - 16)] = r;    // logvar
  }
}

extern "C" void kernel_launch(void* const* d_in, const int* in_sizes, int n_in,
                              void* d_out, int out_size, void* d_ws, size_t ws_size,
                              hipStream_t stream) {
  const float* x   = (const float*)d_in[0];
  const float* adj = (const float*)d_in[1];
  const float* W1  = (const float*)d_in[2];
  const float* b1  = (const float*)d_in[3];
  const float* W2  = (const float*)d_in[4];
  const float* b2  = (const float*)d_in[5];
  const float* Wg  = (const float*)d_in[6];
  const float* a   = (const float*)d_in[7];
  float* out = (float*)d_out;

  char* ws = (char*)d_ws;
  int*   row_cnt  = (int*)  (ws + 0);          //  32 KB
  int*   row_cols = (int*)  (ws + 32768);      //   4 MB
  float* row_vals = (float*)(ws + 4227072);    //   4 MB
  u16*   B1t      = (u16*)  (ws + 8421376);    // 512 KB (256 x 1024)
  u16*   B2t      = (u16*)  (ws + 8945664);    // 256 KB (256 x 512)
  u16*   B3t      = (u16*)  (ws + 9207808);    // 128 KB (128 x 512)
  float* s1       = (float*)(ws + 9338880);    //  32 KB
  float* s2       = (float*)(ws + 9371648);    //  32 KB
  u16*   hbf      = (u16*)  (ws + 9404416);    //   2 MB (8192 x 128 bf16)
  float* H0       = (float*)(ws + 13598720);   //   8 MB (8192 x 256 fp32)
  float* T2       = (float*)(ws + 21987328);   //   8 MB (8192 x 256 fp32)

  // 1. weight pack (tiny; must precede gemm1)
  k_packw<<<896, 256, 0, stream>>>(W1, B1t, W2, B2t, Wg, B3t);
  // 2. merged: GEMM1 (512 compute blocks) + CSR build (8192 HBM blocks) — overlap
  k_csr_gemm1<<<512 + NROW, 256, 0, stream>>>(adj, row_cnt, row_cols, row_vals, x, B1t, H0);
  // 3. fused: T2 = leaky(adj @ H0 + b1) @ W2   (no x1 materialization)
  k_spmm_gemm2<<<512, 256, 0, stream>>>(H0, b1, row_cnt, row_cols, row_vals, B2t, T2);
  // 4. fused: h(bf16) = leaky(adj @ T2 + b2) @ Wg, + fp32 s1/s2
  k_spmm_gemm3<<<512, 256, 0, stream>>>(T2, b2, row_cnt, row_cols, row_vals, B3t, hbf, a, s1, s2);
  // 5. masked softmax attention + aggregate + output split
  k_attn<<<NROW, 128, 0, stream>>>(hbf, s1, s2, row_cnt, row_cols, out);
}

// Round 9
// 469.953 us; speedup vs baseline: 1.0185x; 1.0185x over previous
//
#include <hip/hip_runtime.h>

typedef unsigned short u16;
typedef u16 u16x4 __attribute__((ext_vector_type(4)));
typedef __bf16 bf16x8 __attribute__((ext_vector_type(8)));
typedef float f32x4 __attribute__((ext_vector_type(4)));

#define NROW 8192
#define CAP 128
#define D_IN 512
#define D_HID 256
#define D_OUT 128

__device__ __forceinline__ float leaky_f(float x) { return x > 0.f ? x : 0.25f * x; }

__device__ __forceinline__ u16 f2bf_rne(float f) {
  unsigned u = __float_as_uint(f);
  u += 0x7fffu + ((u >> 16) & 1u);
  return (u16)(u >> 16);
}
__device__ __forceinline__ float bf2f(u16 v) { return __uint_as_float(((unsigned)v) << 16); }
__device__ __forceinline__ void split_bf16(float f, u16& hi, u16& lo) {
  hi = f2bf_rne(f);
  float fh = __uint_as_float(((unsigned)hi) << 16);
  lo = f2bf_rne(f - fh);
}

// ---------------- weight pack: one thread per (n, k-octet); coalesced 16B stores ----------------
// W (K x Nc fp32, k-major) -> Bt rows [hi(K)|lo(K)]. Loads scattered (L2-absorbed, W tiny);
// stores: consecutive tids share n with consecutive k-octets -> contiguous u16x8 writes.
__global__ __launch_bounds__(256) void k_packw(
    const float* __restrict__ W1, u16* __restrict__ B1,
    const float* __restrict__ W2, u16* __restrict__ B2,
    const float* __restrict__ Wg, u16* __restrict__ B3) {
  const float* W; u16* Bt; int K, Nc, idx;
  int pb = blockIdx.x;                     // 112 blocks: 64 (W1) | 32 (W2) | 16 (Wg)
  if (pb < 64)      { W = W1; Bt = B1; K = D_IN;  Nc = D_HID; idx = pb * 256 + threadIdx.x; }
  else if (pb < 96) { W = W2; Bt = B2; K = D_HID; Nc = D_HID; idx = (pb - 64) * 256 + threadIdx.x; }
  else              { W = Wg; Bt = B3; K = D_HID; Nc = D_OUT; idx = (pb - 96) * 256 + threadIdx.x; }
  int ko8 = K >> 3;
  int n = idx / ko8, k0 = (idx % ko8) << 3;
  alignas(16) u16 hh[8], ll[8];
#pragma unroll
  for (int j = 0; j < 8; ++j) {
    float f = W[(size_t)(k0 + j) * Nc + n];
    split_bf16(f, hh[j], ll[j]);
  }
  size_t ro = (size_t)n * 2 * K;
  *(uint4*)(Bt + ro + k0)     = *(const uint4*)hh;
  *(uint4*)(Bt + ro + K + k0) = *(const uint4*)ll;
}

// ---------------- merged: blocks [0,512) = GEMM1 (x @ W1), blocks [512,8704) = CSR build ----------------
__global__ __launch_bounds__(256) void k_csr_gemm1(const float* __restrict__ adj,
    int* __restrict__ cnt, int* __restrict__ cols, float* __restrict__ vals,
    const float* __restrict__ X, const u16* __restrict__ Bt, float* __restrict__ C) {
  __shared__ u16 Ah[64 * 40], Al[64 * 40];
  __shared__ u16 Bh[64 * 40], Bl[64 * 40];
  __shared__ int csrc;
  int b = blockIdx.x;
  int tid = threadIdx.x;
  if (b < 512) {  // GEMM1: 64x64 tile, in-register fp32->split-bf16 of x; K=512, N=256
    const int N = D_HID, K = D_IN;
    int bm = (b >> 2) * 64, bn = (b & 3) * 64;
    int wave = tid >> 6, lane = tid & 63, l15 = lane & 15, quad = lane >> 4;
    f32x4 acc[4] = {};
    int ar = tid >> 2, aj = (tid & 3) << 3;
    const float* Xrow = X + (size_t)(bm + ar) * K + aj;
    const u16* Brow = Bt + (size_t)(bn + ar) * (2 * K) + aj;
    for (int k0 = 0; k0 < K; k0 += 32) {
      alignas(16) u16 hh[8], ll[8];
      float xv[8];
      *(float4*)(xv)     = *(const float4*)(Xrow + k0);
      *(float4*)(xv + 4) = *(const float4*)(Xrow + k0 + 4);
#pragma unroll
      for (int e = 0; e < 8; ++e) split_bf16(xv[e], hh[e], ll[e]);
      *(uint4*)(&Ah[ar * 40 + aj]) = *(const uint4*)hh;
      *(uint4*)(&Al[ar * 40 + aj]) = *(const uint4*)ll;
      *(uint4*)(&Bh[ar * 40 + aj]) = *(const uint4*)(Brow + k0);
      *(uint4*)(&Bl[ar * 40 + aj]) = *(const uint4*)(Brow + K + k0);
      __syncthreads();
      bf16x8 afh = *(const bf16x8*)(&Ah[(wave * 16 + l15) * 40 + quad * 8]);
      bf16x8 afl = *(const bf16x8*)(&Al[(wave * 16 + l15) * 40 + quad * 8]);
#pragma unroll
      for (int c = 0; c < 4; ++c) {
        bf16x8 bfh = *(const bf16x8*)(&Bh[(c * 16 + l15) * 40 + quad * 8]);
        bf16x8 bfl = *(const bf16x8*)(&Bl[(c * 16 + l15) * 40 + quad * 8]);
        acc[c] = __builtin_amdgcn_mfma_f32_16x16x32_bf16(afh, bfh, acc[c], 0, 0, 0);
        acc[c] = __builtin_amdgcn_mfma_f32_16x16x32_bf16(afh, bfl, acc[c], 0, 0, 0);
        acc[c] = __builtin_amdgcn_mfma_f32_16x16x32_bf16(afl, bfh, acc[c], 0, 0, 0);
      }
      __syncthreads();
    }
#pragma unroll
    for (int c = 0; c < 4; ++c)
#pragma unroll
      for (int rg = 0; rg < 4; ++rg) {
        int rowi = bm + wave * 16 + quad * 4 + rg;   // C/D: col=lane&15, row=quad*4+reg
        int coli = bn + c * 16 + l15;
        C[(size_t)rowi * N + coli] = acc[c][rg];
      }
    return;
  }
  // CSR row build
  int i = b - 512;
  if (tid == 0) csrc = 0;
  __syncthreads();
  const float4* row = (const float4*)(adj + (size_t)i * NROW);
  for (int j4 = tid; j4 < NROW / 4; j4 += 256) {
    float4 v = row[j4];
    int base = j4 * 4;
    if (v.x > 0.f) { int s = atomicAdd(&csrc, 1); if (s < CAP) { cols[i*CAP+s] = base;   vals[i*CAP+s] = v.x; } }
    if (v.y > 0.f) { int s = atomicAdd(&csrc, 1); if (s < CAP) { cols[i*CAP+s] = base+1; vals[i*CAP+s] = v.y; } }
    if (v.z > 0.f) { int s = atomicAdd(&csrc, 1); if (s < CAP) { cols[i*CAP+s] = base+2; vals[i*CAP+s] = v.z; } }
    if (v.w > 0.f) { int s = atomicAdd(&csrc, 1); if (s < CAP) { cols[i*CAP+s] = base+3; vals[i*CAP+s] = v.w; } }
  }
  __syncthreads();
  if (tid == 0) cnt[i] = (csrc < CAP) ? csrc : CAP;
}

// ---------------- GEMM2: 64x64 tile, packed A; grid (N/64, M/64) ----------------
__global__ __launch_bounds__(256) void k_gemm(const u16* __restrict__ A, const u16* __restrict__ Bt,
    float* __restrict__ C, int N, int K) {
  __shared__ u16 Ah[64 * 40], Al[64 * 40];
  __shared__ u16 Bh[64 * 40], Bl[64 * 40];
  int tid = threadIdx.x;
  int bm = blockIdx.y * 64, bn = blockIdx.x * 64;
  int wave = tid >> 6, lane = tid & 63, l15 = lane & 15, quad = lane >> 4;
  f32x4 acc[4] = {};
  int ar = tid >> 2, aj = (tid & 3) << 3;
  const u16* Arow = A + (size_t)(bm + ar) * (2 * K) + aj;
  const u16* Brow = Bt + (size_t)(bn + ar) * (2 * K) + aj;
  for (int k0 = 0; k0 < K; k0 += 32) {
    *(uint4*)(&Ah[ar * 40 + aj]) = *(const uint4*)(Arow + k0);
    *(uint4*)(&Al[ar * 40 + aj]) = *(const uint4*)(Arow + K + k0);
    *(uint4*)(&Bh[ar * 40 + aj]) = *(const uint4*)(Brow + k0);
    *(uint4*)(&Bl[ar * 40 + aj]) = *(const uint4*)(Brow + K + k0);
    __syncthreads();
    bf16x8 afh = *(const bf16x8*)(&Ah[(wave * 16 + l15) * 40 + quad * 8]);
    bf16x8 afl = *(const bf16x8*)(&Al[(wave * 16 + l15) * 40 + quad * 8]);
#pragma unroll
    for (int c = 0; c < 4; ++c) {
      bf16x8 bfh = *(const bf16x8*)(&Bh[(c * 16 + l15) * 40 + quad * 8]);
      bf16x8 bfl = *(const bf16x8*)(&Bl[(c * 16 + l15) * 40 + quad * 8]);
      acc[c] = __builtin_amdgcn_mfma_f32_16x16x32_bf16(afh, bfh, acc[c], 0, 0, 0);
      acc[c] = __builtin_amdgcn_mfma_f32_16x16x32_bf16(afh, bfl, acc[c], 0, 0, 0);
      acc[c] = __builtin_amdgcn_mfma_f32_16x16x32_bf16(afl, bfh, acc[c], 0, 0, 0);
    }
    __syncthreads();
  }
#pragma unroll
  for (int c = 0; c < 4; ++c)
#pragma unroll
    for (int rg = 0; rg < 4; ++rg) {
      int rowi = bm + wave * 16 + quad * 4 + rg;
      int coli = bn + c * 16 + l15;
      C[(size_t)rowi * N + coli] = acc[c][rg];
    }
}

// ---------------- GEMM3: 32x128 tile (N==128); h out in bf16; fused s1/s2 (fp32-exact) ----------------
__global__ __launch_bounds__(256) void k_gemm3(const u16* __restrict__ A, const u16* __restrict__ Bt,
    u16* __restrict__ Hb, int K,
    const float* __restrict__ aptr, float* __restrict__ s1, float* __restrict__ s2) {
  __shared__ u16 Ah[32 * 40], Al[32 * 40];
  __shared__ u16 Bh[128 * 40], Bl[128 * 40];
  __shared__ float sp1[2][32], sp2[2][32];
  int tid = threadIdx.x;
  int bm = blockIdx.y * 32;
  int wave = tid >> 6, lane = tid & 63, l15 = lane & 15, quad = lane >> 4;
  int rhalf = wave >> 1, chalf = wave & 1;
  f32x4 acc[4] = {};
  int t7 = tid & 127;
  int ar = t7 >> 2, aj = (t7 & 3) << 3;
  int br = tid >> 1, bj = (tid & 1) << 4;
  const u16* Arow = A + (size_t)(bm + ar) * (2 * K) + aj + (tid < 128 ? 0 : K);
  u16* Adst = (tid < 128 ? Ah : Al) + ar * 40 + aj;
  const u16* Brow = Bt + (size_t)br * (2 * K) + bj;
  for (int k0 = 0; k0 < K; k0 += 32) {
    *(uint4*)Adst = *(const uint4*)(Arow + k0);
#pragma unroll
    for (int jj = 0; jj < 2; ++jj) {
      *(uint4*)(&Bh[br * 40 + bj + jj * 8]) = *(const uint4*)(Brow + k0 + jj * 8);
      *(uint4*)(&Bl[br * 40 + bj + jj * 8]) = *(const uint4*)(Brow + K + k0 + jj * 8);
    }
    __syncthreads();
    bf16x8 afh = *(const bf16x8*)(&Ah[(rhalf * 16 + l15) * 40 + quad * 8]);
    bf16x8 afl = *(const bf16x8*)(&Al[(rhalf * 16 + l15) * 40 + quad * 8]);
#pragma unroll
    for (int c = 0; c < 4; ++c) {
      bf16x8 bfh = *(const bf16x8*)(&Bh[(chalf * 64 + c * 16 + l15) * 40 + quad * 8]);
      bf16x8 bfl = *(const bf16x8*)(&Bl[(chalf * 64 + c * 16 + l15) * 40 + quad * 8]);
      acc[c] = __builtin_amdgcn_mfma_f32_16x16x32_bf16(afh, bfh, acc[c], 0, 0, 0);
      acc[c] = __builtin_amdgcn_mfma_f32_16x16x32_bf16(afh, bfl, acc[c], 0, 0, 0);
      acc[c] = __builtin_amdgcn_mfma_f32_16x16x32_bf16(afl, bfh, acc[c], 0, 0, 0);
    }
    __syncthreads();
  }
  // h write (bf16; only att@h consumes it — logits below from fp32 accs)
#pragma unroll
  for (int c = 0; c < 4; ++c)
#pragma unroll
    for (int rg = 0; rg < 4; ++rg) {
      int rowi = bm + rhalf * 16 + quad * 4 + rg;
      int coli = chalf * 64 + c * 16 + l15;
      Hb[(size_t)rowi * 128 + coli] = f2bf_rne(acc[c][rg]);
    }
  // fused s1/s2 from fp32 accumulators (exact logit path)
  float a1v[4], a2v[4];
#pragma unroll
  for (int c = 0; c < 4; ++c) {
    a1v[c] = aptr[chalf * 64 + c * 16 + l15];
    a2v[c] = aptr[128 + chalf * 64 + c * 16 + l15];
  }
#pragma unroll
  for (int rg = 0; rg < 4; ++rg) {
    float p1 = 0.f, p2 = 0.f;
#pragma unroll
    for (int c = 0; c < 4; ++c) { p1 = fmaf(acc[c][rg], a1v[c], p1); p2 = fmaf(acc[c][rg], a2v[c], p2); }
#pragma unroll
    for (int m = 1; m < 16; m <<= 1) { p1 += __shfl_xor(p1, m); p2 += __shfl_xor(p2, m); }
    if (l15 == 0) {
      int rloc = rhalf * 16 + quad * 4 + rg;
      sp1[chalf][rloc] = p1; sp2[chalf][rloc] = p2;
    }
  }
  __syncthreads();
  if (tid < 32) {
    s1[bm + tid] = sp1[0][tid] + sp1[1][tid];
    s2[bm + tid] = sp2[0][tid] + sp2[1][tid];
  }
}

// ---------------- SpMM + bias + leaky + 2K-split-pack (fp32 H input — exact) ----------------
__global__ __launch_bounds__(256) void k_spmm_pack(const float* __restrict__ Hin,
    const float* __restrict__ bias, const int* __restrict__ cnt,
    const int* __restrict__ cols, const float* __restrict__ vals, u16* __restrict__ Ap) {
  int i = blockIdx.x, t = threadIdx.x;
  int t64 = t & 63, g = t >> 6;
  __shared__ int sc[CAP];
  __shared__ float sv[CAP];
  __shared__ float4 sacc[4][64];
  int n = cnt[i];
  if (t < n) { sc[t] = cols[i * CAP + t]; sv[t] = vals[i * CAP + t]; }
  __syncthreads();
  float4 acc = {0.f, 0.f, 0.f, 0.f};
  const float4* H4 = (const float4*)Hin;
  for (int k = g; k < n; k += 4) {
    float w = sv[k];
    float4 v = H4[(size_t)sc[k] * 64 + t64];
    acc.x = fmaf(w, v.x, acc.x); acc.y = fmaf(w, v.y, acc.y);
    acc.z = fmaf(w, v.z, acc.z); acc.w = fmaf(w, v.w, acc.w);
  }
  sacc[g][t64] = acc;
  __syncthreads();
  if (t < 64) {
    float4 a0 = sacc[0][t], a1 = sacc[1][t], a2 = sacc[2][t], a3 = sacc[3][t];
    float4 bv = ((const float4*)bias)[t];
    float r[4] = { leaky_f(a0.x + a1.x + a2.x + a3.x + bv.x),
                   leaky_f(a0.y + a1.y + a2.y + a3.y + bv.y),
                   leaky_f(a0.z + a1.z + a2.z + a3.z + bv.z),
                   leaky_f(a0.w + a1.w + a2.w + a3.w + bv.w) };
    u16x4 hi4, lo4;
#pragma unroll
    for (int e = 0; e < 4; ++e) { u16 hh, ll; split_bf16(r[e], hh, ll); hi4[e] = hh; lo4[e] = ll; }
    size_t ro = (size_t)i * 512;
    *(u16x4*)(Ap + ro + 4 * t) = hi4;
    *(u16x4*)(Ap + ro + 256 + 4 * t) = lo4;
  }
}

// ---------------- attention: fp32 logits, bf16 h gather, mu/logvar split ----------------
__global__ __launch_bounds__(128) void k_attn(const u16* __restrict__ Hb,
    const float* __restrict__ s1, const float* __restrict__ s2,
    const int* __restrict__ cnt, const int* __restrict__ cols, float* __restrict__ out) {
  int i = blockIdx.x, t = threadIdx.x;
  int t32 = t & 31, g = t >> 5;
  __shared__ int sc[CAP];
  __shared__ float sw[CAP];
  __shared__ float sred[2];
  __shared__ float4 sacc[4][32];
  int n = cnt[i];
  float s1i = s1[i];
  if (t < n) { int c = cols[i * CAP + t]; sc[t] = c; sw[t] = leaky_f(s1i + s2[c]); }
  __syncthreads();
  if (t < 64) {
    float m = -1e30f;
    if (t < n) m = sw[t];
    if (t + 64 < n) m = fmaxf(m, sw[t + 64]);
    for (int o = 32; o > 0; o >>= 1) m = fmaxf(m, __shfl_down(m, o));
    if (t == 0) sred[0] = m;
  }
  __syncthreads();
  float mx = sred[0];
  if (t < n) sw[t] = expf(sw[t] - mx);
  __syncthreads();
  if (t < 64) {
    float s = 0.f;
    if (t < n) s = sw[t];
    if (t + 64 < n) s += sw[t + 64];
    for (int o = 32; o > 0; o >>= 1) s += __shfl_down(s, o);
    if (t == 0) sred[1] = s;
  }
  __syncthreads();
  float inv = (n > 0) ? 1.0f / sred[1] : 0.f;
  float4 acc = {0.f, 0.f, 0.f, 0.f};
  for (int k = g; k < n; k += 4) {
    float w = sw[k];
    u16x4 v = *(const u16x4*)(Hb + (size_t)sc[k] * 128 + 4 * t32);
    acc.x = fmaf(w, bf2f(v[0]), acc.x); acc.y = fmaf(w, bf2f(v[1]), acc.y);
    acc.z = fmaf(w, bf2f(v[2]), acc.z); acc.w = fmaf(w, bf2f(v[3]), acc.w);
  }
  sacc[g][t32] = acc;
  __syncthreads();
  if (t < 32) {
    float4 a0 = sacc[0][t], a1 = sacc[1][t], a2 = sacc[2][t], a3 = sacc[3][t];
    float4 r;
    r.x = leaky_f((a0.x + a1.x + a2.x + a3.x) * inv);
    r.y = leaky_f((a0.y + a1.y + a2.y + a3.y) * inv);
    r.z = leaky_f((a0.z + a1.z + a2.z + a3.z) * inv);
    r.w = leaky_f((a0.w + a1.w + a2.w + a3.w) * inv);
    float4* o4 = (float4*)out;
    if (t < 16) o4[(size_t)i * 16 + t] = r;                               // mu
    else        o4[(size_t)NROW * 16 + (size_t)i * 16 + (t - 16)] = r;    // logvar
  }
}

extern "C" void kernel_launch(void* const* d_in, const int* in_sizes, int n_in,
                              void* d_out, int out_size, void* d_ws, size_t ws_size,
                              hipStream_t stream) {
  const float* x   = (const float*)d_in[0];
  const float* adj = (const float*)d_in[1];
  const float* W1  = (const float*)d_in[2];
  const float* b1  = (const float*)d_in[3];
  const float* W2  = (const float*)d_in[4];
  const float* b2  = (const float*)d_in[5];
  const float* Wg  = (const float*)d_in[6];
  const float* a   = (const float*)d_in[7];
  float* out = (float*)d_out;

  char* ws = (char*)d_ws;
  int*   row_cnt  = (int*)  (ws + 0);          //  32 KB
  int*   row_cols = (int*)  (ws + 32768);      //   4 MB
  float* row_vals = (float*)(ws + 4227072);    //   4 MB
  u16*   B1t      = (u16*)  (ws + 8421376);    // 512 KB (256 x 1024)
  u16*   B2t      = (u16*)  (ws + 8945664);    // 256 KB (256 x 512)
  u16*   B3t      = (u16*)  (ws + 9207808);    // 128 KB (128 x 512)
  float* s1       = (float*)(ws + 9338880);    //  32 KB
  float* s2       = (float*)(ws + 9371648);    //  32 KB
  u16*   hbf      = (u16*)  (ws + 9404416);    //   2 MB (8192 x 128 bf16)
  float* H0T2     = (float*)(ws + 13598720);   //   8 MB (8192 x 256 fp32)
  u16*   Apack    = (u16*)  (ws + 21987328);   //   8 MB (8192 x 512), x1/x2 packed

  // 1. weight pack (coalesced-store mapping; must precede gemm1)
  k_packw<<<112, 256, 0, stream>>>(W1, B1t, W2, B2t, Wg, B3t);
  // 2. merged: GEMM1 (512 compute blocks) + CSR build (8192 HBM blocks) — overlap
  k_csr_gemm1<<<512 + NROW, 256, 0, stream>>>(adj, row_cnt, row_cols, row_vals, x, B1t, H0T2);
  // 3. x1 = leaky(adj @ H0 + b1) -> packed
  k_spmm_pack<<<NROW, 256, 0, stream>>>(H0T2, b1, row_cnt, row_cols, row_vals, Apack);
  // 4. T2 = x1 @ W2  (K=256)
  k_gemm<<<dim3(4, 128), 256, 0, stream>>>(Apack, B2t, H0T2, D_HID, D_HID);
  // 5. x2 = leaky(adj @ T2 + b2) -> packed
  k_spmm_pack<<<NROW, 256, 0, stream>>>(H0T2, b2, row_cnt, row_cols, row_vals, Apack);
  // 6. h (bf16) = x2 @ Wg + fused fp32 s1/s2
  k_gemm3<<<dim3(1, 256), 256, 0, stream>>>(Apack, B3t, hbf, D_HID, a, s1, s2);
  // 7. masked softmax attention (fp32 logits) + bf16 aggregate + output split
  k_attn<<<NROW, 128, 0, stream>>>(hbf, s1, s2, row_cnt, row_cols, out);
}